// Round 3
// baseline (167.503 us; speedup 1.0000x reference)
//
#include <hip/hip_runtime.h>

// ---------------------------------------------------------------------------
// SelfAttentionLayer: out[b,s,c*16+h] = softmax_k( (q.k)/32 masked ) @ v
// R9: R8 base (G=2 heads/block, 8 waves) + correctly-swizzled BK=32
// double-buffered GEMM pipeline (T3 min-2-phase + T4 counted vmcnt).
// R7's pipeline failed on a wrong swizzle key ((row&3) -> 4-way conflict);
// for 64 B rows the bank-slot is 16*(row&1)+4*chunk, so the key must be
// ((row>>1)&3): rows r,r+8 become 2-way (free, m136). LDS footprint is
// unchanged (2x16KB X + 2x6KB W = 44 KB), addresses are loop-invariant,
// buffers selected at compile time via explicit 2x unroll.
// ---------------------------------------------------------------------------

typedef unsigned short u16;
typedef unsigned int u32;
typedef __attribute__((ext_vector_type(8))) short short8;
typedef __attribute__((ext_vector_type(4))) short short4v;
typedef __attribute__((ext_vector_type(4))) float floatx4;

#if __has_builtin(__builtin_amdgcn_mfma_f32_16x16x16bf16_1k)
#define MFMA16(A, B, C) __builtin_amdgcn_mfma_f32_16x16x16bf16_1k(A, B, C, 0, 0, 0)
#elif __has_builtin(__builtin_amdgcn_mfma_f32_16x16x16_bf16)
#define MFMA16(A, B, C) __builtin_amdgcn_mfma_f32_16x16x16_bf16(A, B, C, 0, 0, 0)
#else
__device__ __forceinline__ floatx4 mfma16_asm(short4v a, short4v b, floatx4 c) {
  floatx4 d;
  asm volatile("v_mfma_f32_16x16x16_bf16 %0, %1, %2, %3"
               : "=v"(d) : "v"(a), "v"(b), "v"(c));
  return d;
}
#define MFMA16(A, B, C) mfma16_asm(A, B, C)
#endif

#if __has_builtin(__builtin_amdgcn_exp2f)
#define EXP2(x) __builtin_amdgcn_exp2f(x)
#else
#define EXP2(x) __expf((x) * 0.6931471805599453f)
#endif

#define QSCALE 0.045084220f  // log2(e)/32, folded into Q

__device__ __forceinline__ u16 f2bf(float f) {
  union { float f; u32 u; } x; x.f = f;
  u32 r = x.u + 0x7fffu + ((x.u >> 16) & 1u);  // RNE
  return (u16)(r >> 16);
}
__device__ __forceinline__ float bf2f(u16 u) {
  union { u32 u; float f; } x; x.u = ((u32)u) << 16;
  return x.f;
}

// async global->LDS, 16B per lane; LDS dest = wave-uniform base + lane*16
__device__ __forceinline__ void gload16(const void* g, void* l) {
  typedef __attribute__((address_space(1))) const unsigned int gq;
  typedef __attribute__((address_space(3))) unsigned int lq;
  __builtin_amdgcn_global_load_lds((gq*)(size_t)g, (lq*)(size_t)l, 16, 0, 0);
}

#define GK 1024
#define QKS 20   // Qs/Ks row stride (u16): 8B-aligned frags, conflict-free
#define VTS 264  // Vt row stride (u16): 2-way-max banks (free)

// ---------------------------------------------------------------------------
// Merged cast f32 -> bf16: X (8192 blocks), Wq/Wk/Wv (1024 blocks each)
// ---------------------------------------------------------------------------
__global__ __launch_bounds__(256) void cast_all(const float* __restrict__ x,
                                                const float* __restrict__ wq,
                                                const float* __restrict__ wk,
                                                const float* __restrict__ wv,
                                                u16* __restrict__ XB,
                                                u16* __restrict__ WB) {
  int bid = blockIdx.x;
  const float* src; u16* dst; int off;
  if (bid < 8192)       { src = x;  dst = XB;                 off = bid; }
  else if (bid < 9216)  { src = wq; dst = WB;                 off = bid - 8192; }
  else if (bid < 10240) { src = wk; dst = WB + 1024 * 1024;   off = bid - 9216; }
  else                  { src = wv; dst = WB + 2 * 1024 * 1024; off = bid - 10240; }
  int i = (off * 256 + threadIdx.x) * 4;
  float4 v = *(const float4*)(src + i);
  u32 lo = (u32)f2bf(v.x) | ((u32)f2bf(v.y) << 16);
  u32 hi = (u32)f2bf(v.z) | ((u32)f2bf(v.w) << 16);
  uint2 o; o.x = lo; o.y = hi;
  *(uint2*)(dst + i) = o;
}

// ---------------------------------------------------------------------------
// Attn kt-loop (R5-verified math, LDS sources): S^T = MFMA(K, Qscaled);
// p = exp2(st) trunc-packed via v_perm; l via MFMA(ones,p); O^T += MFMA(V^T,p)
// qt=2: each of the 8 waves owns a 32-row q-strip.
// ---------------------------------------------------------------------------
template <bool MASKED>
__device__ __forceinline__ void attn_loop2(const u16* __restrict__ Ks,
                                           const u16* __restrict__ Vt,
                                           const short4v* bq, const float* mqv,
                                           const float* m_s,
                                           floatx4* oacc, floatx4* lacc,
                                           int col, int quad) {
  const short4v ones = {(short)0x3F80, (short)0x3F80, (short)0x3F80, (short)0x3F80};
#pragma unroll 4
  for (int kt = 0; kt < 16; kt++) {
    const int kb = kt * 16;
    short4v ak = *(const short4v*)(Ks + (kb + col) * QKS + quad * 4);
    short4v av = *(const short4v*)(Vt + col * VTS + kb + quad * 4);
    float mk[4];
    if (MASKED) {
#pragma unroll
      for (int i = 0; i < 4; i++) mk[i] = m_s[kb + quad * 4 + i];
    }
#pragma unroll
    for (int qt = 0; qt < 2; qt++) {
      floatx4 z = {0.f, 0.f, 0.f, 0.f};
      floatx4 st = MFMA16(ak, bq[qt], z);
      float e[4];
#pragma unroll
      for (int i = 0; i < 4; i++) {
        e[i] = EXP2(st[i]);
        if (MASKED) e[i] = (mqv[qt] * mk[i] > 0.f) ? e[i] : 0.f;
      }
      union { u32 u[2]; short4v s; } pk;
      pk.u[0] = __builtin_amdgcn_perm(__float_as_uint(e[1]), __float_as_uint(e[0]), 0x07060302u);
      pk.u[1] = __builtin_amdgcn_perm(__float_as_uint(e[3]), __float_as_uint(e[2]), 0x07060302u);
      lacc[qt] = MFMA16(ones, pk.s, lacc[qt]);
      oacc[qt] = MFMA16(av, pk.s, oacc[qt]);
    }
  }
}

// ---------------------------------------------------------------------------
// Fused kernel. Block = (c0 = (bid>>5)*2 heads, b = bid&31); grid 1024.
// Same-b blocks -> same XCD (bid%8 = b%8): X[b] (512 KB) stays L2-resident.
// Phase 1 (GEMM, pipelined): [256,96] = X[b][256,1024] @ Wslice[96,1024]^T.
//   BK=32 double-buffered. Per iter: issue DMA(t+1) -> s_waitcnt vmcnt(3/2)
//   (never 0 in-loop) -> s_barrier -> 8 ds_read_b128 + 12 MFMA -> lgkmcnt(0)
//   -> s_barrier. Swizzle: 64 B rows, 4 chunks of 16 B; physical chunk p of
//   row r holds logical p^((r>>1)&3); read chunk = quad^((col>>1)&3).
//   Bank-slot = 16*(r&1)+4*chunk -> worst aliasing 2-way (rows r, r+8) = free.
// Phase 2 (x2 heads, sequential): Q,K (stride-20) + V^T (stride-264) in LDS ->
//   attn_loop2 -> ot -> epilogue store.
// LDS: GEMM Xs 2x[256][32]@0/@16KB + Ws 2x[96][32]@32KB/@38KB = 44 KB; attn
// (29.3 KB) overlays; +1 KB m_s -> ~46 KB block.
// ---------------------------------------------------------------------------
__global__ __launch_bounds__(512, 4) void fused_qkv_attn(const u16* __restrict__ XB,
                                                         const u16* __restrict__ WB,
                                                         const float* __restrict__ mask,
                                                         float* __restrict__ out) {
  __shared__ __align__(16) u16 smem[22528];  // 45056 B
  // GEMM: Xs0@0 (256*32), Xs1@8192, Ws0@16384 (96*32), Ws1@19456
  // attn: Qs@0 (256*20), Ks@5120, Vt@10240 (16*264), l_s@14464 (256 f32),
  //       ot overlays @0 (16*257 f32 = 16448 B < Vt base 20480 B)
  __shared__ float m_s[256];

  const int bid = blockIdx.x;
  const int b = bid & 31;
  const int c0 = (bid >> 5) * 2;       // first of 2 heads
  const int t = threadIdx.x;
  const int wave = t >> 6;             // 0..7
  const int lane = t & 63;
  const int col = lane & 15;
  const int quad = lane >> 4;

  u16* const Xs0 = smem;
  u16* const Xs1 = smem + 8192;
  u16* const Ws0 = smem + 16384;
  u16* const Ws1 = smem + 19456;

  float mv = (t < 256) ? mask[b * 256 + t] : 1.0f;
  if (t < 256) m_s[t] = mv;
  const int allones = __syncthreads_and(mv > 0.f);

  // ---------------- phase 1: pipelined GEMM ----------------
  // Per tile (BK=32): X = 256 rows x 64 B; wave stages its 32 rows as 2
  // gload16 (16 rows x 4 chunks each, lane -> row lane>>2, chunk lane&3).
  // W = 96 rows; waves 0..5 stage 16 rows each (1 gload16).
  const int rl = lane >> 2;            // 0..15: row within 16-row group
  const int ch = lane & 3;             // dest chunk (16 B)
  const int sch = ch ^ ((rl >> 1) & 3);  // swizzled source chunk

  const size_t xsrc = ((size_t)b * 256 + wave * 32 + rl) * GK + sch * 8;
  const int xdst = wave * 1024;        // u16: (wave*32 rows)*32; + g*512

  size_t wsrc = 0;
  if (wave < 6)  // wave w stages Ws rows w*16+rl: matrix w%3, head c0+w/3
    wsrc = ((size_t)((wave % 3) * 1024 + (c0 + wave / 3) * 16 + rl)) * GK + sch * 8;
  const int wdst = wave * 512;

  floatx4 acc[2][6] = {};  // [mt][nt]: m = wave*32+mt*16; nt = head*3+{Q,K,V}

  // read-side un-swizzle: logical chunk quad lives at quad^((col>>1)&3)
  const int rpos = (quad ^ ((col >> 1) & 3)) * 8;
  const int arow0 = (wave * 32 + col) * 32 + rpos;     // af: + mt*512
                                                       // bf: (nt*16+col)*32+rpos

  // prologue: stage tile 0 into buf0 (3 loads in flight; waves 6,7: 2)
  gload16(XB + xsrc, Xs0 + xdst);
  gload16(XB + xsrc + (size_t)16 * GK, Xs0 + xdst + 512);
  if (wave < 6) gload16(WB + wsrc, Ws0 + wdst);

  auto gemm_step = [&](int knext, const u16* Xc, const u16* Wc, u16* Xn, u16* Wn) {
    if (knext >= 0) {
      gload16(XB + xsrc + knext, Xn + xdst);
      gload16(XB + xsrc + (size_t)16 * GK + knext, Xn + xdst + 512);
      if (wave < 6) {
        gload16(WB + wsrc + knext, Wn + wdst);
        asm volatile("s_waitcnt vmcnt(3)" ::: "memory");  // prev tile's 3 done
      } else {
        asm volatile("s_waitcnt vmcnt(2)" ::: "memory");
      }
    } else {
      asm volatile("s_waitcnt vmcnt(0)" ::: "memory");    // final tile: drain
    }
    __builtin_amdgcn_sched_barrier(0);
    __builtin_amdgcn_s_barrier();      // all waves' DMA for cur tile landed
    __builtin_amdgcn_sched_barrier(0); // keep ds_reads below the barrier

    short8 af[2], bf[6];
#pragma unroll
    for (int mt = 0; mt < 2; mt++)
      af[mt] = *(const short8*)(Xc + arow0 + mt * 512);
#pragma unroll
    for (int nt = 0; nt < 6; nt++)
      bf[nt] = *(const short8*)(Wc + (nt * 16 + col) * 32 + rpos);
#pragma unroll
    for (int mt = 0; mt < 2; mt++)
#pragma unroll
      for (int nt = 0; nt < 6; nt++)
        acc[mt][nt] = __builtin_amdgcn_mfma_f32_16x16x32_bf16(af[mt], bf[nt], acc[mt][nt], 0, 0, 0);

    asm volatile("s_waitcnt lgkmcnt(0)" ::: "memory");  // my reads of cur done
    __builtin_amdgcn_sched_barrier(0);
    __builtin_amdgcn_s_barrier();      // cur buf safe to overwrite next iter
  };

  // tile tt lives in buf (tt&1); iter tt computes tt, issues tt+1
#pragma unroll 1
  for (int tp = 0; tp < 15; tp++) {
    gemm_step((2 * tp + 1) * 32, Xs0, Ws0, Xs1, Ws1);  // tt = 2tp
    gemm_step((2 * tp + 2) * 32, Xs1, Ws1, Xs0, Ws0);  // tt = 2tp+1
  }
  gemm_step(31 * 32, Xs0, Ws0, Xs1, Ws1);  // tt = 30
  gemm_step(-1, Xs1, Ws1, Xs0, Ws0);       // tt = 31 (drain)

  // ---------------- phase 2: attention, 2 heads sequentially ----------------
  u16* const Qs = smem;               // [256][QKS]
  u16* const Ks = smem + 5120;        // [256][QKS]
  u16* const Vt = smem + 10240;       // [16][VTS]
  float* const l_s = (float*)(smem + 14464);
  float* const ot = (float*)smem;     // [16][257] f32, overlays Qs+Ks

#pragma unroll      // full unroll: h must be compile-time (static acc indices)
  for (int h = 0; h < 2; h++) {
    __syncthreads();  // h=0: GEMM done (redundant w/ final barrier, harmless)

    // C/D layout: row = m-base + quad*4 + r, col(head feature) = lane&15
#pragma unroll
    for (int mt = 0; mt < 2; mt++) {
      const int row = wave * 32 + mt * 16 + quad * 4;
#pragma unroll
      for (int r = 0; r < 4; r++) {
        Qs[(row + r) * QKS + col] = f2bf(acc[mt][3 * h + 0][r] * QSCALE);
        Ks[(row + r) * QKS + col] = f2bf(acc[mt][3 * h + 1][r]);
        Vt[col * VTS + row + r] = f2bf(acc[mt][3 * h + 2][r]);
      }
    }
    __syncthreads();

    const int q0 = wave * 32;
    short4v bq[2];
    float mqv[2];
#pragma unroll
    for (int qt = 0; qt < 2; qt++) {
      bq[qt] = *(const short4v*)(Qs + (q0 + qt * 16 + col) * QKS + quad * 4);
      mqv[qt] = m_s[q0 + qt * 16 + col];
    }

    floatx4 oacc[2] = {};
    floatx4 lacc[2] = {};
    if (allones)
      attn_loop2<false>(Ks, Vt, bq, mqv, m_s, oacc, lacc, col, quad);
    else
      attn_loop2<true>(Ks, Vt, bq, mqv, m_s, oacc, lacc, col, quad);

    __syncthreads();  // all waves out of attn before ot overlays Qs/Ks
#pragma unroll
    for (int qt = 0; qt < 2; qt++) {
      if (quad == 0) l_s[q0 + qt * 16 + col] = lacc[qt][0];
#pragma unroll
      for (int r = 0; r < 4; r++)
        ot[(quad * 4 + r) * 257 + q0 + qt * 16 + col] = oacc[qt][r];
    }
    __syncthreads();

    // epilogue: thread t -> q-row t>>1, features hb..hb+8; 32B coalesced
    const int row = t >> 1;
    const int hb = (t & 1) * 8;
    float l = l_s[row];
    float* op = out + ((size_t)b * 256 + row) * 1024 + (c0 + h) * 16 + hb;
    float o[8];
    if (allones || l > 0.f) {
      float inv = 1.0f / l;
#pragma unroll
      for (int j = 0; j < 8; j++) o[j] = ot[(hb + j) * 257 + row] * inv;
    } else {
      // fully-masked row: reference softmax of uniform -1e9 -> mean of V
#pragma unroll
      for (int j = 0; j < 8; j++) o[j] = 0.f;
      for (int k = 0; k < 256; k++)
#pragma unroll
        for (int j = 0; j < 8; j++) o[j] += bf2f(Vt[(hb + j) * VTS + k]);
#pragma unroll
      for (int j = 0; j < 8; j++) o[j] *= (1.0f / 256.0f);
    }
#pragma unroll
    for (int g = 0; g < 2; g++) {
      float4 r;
      r.x = o[g * 4 + 0]; r.y = o[g * 4 + 1]; r.z = o[g * 4 + 2]; r.w = o[g * 4 + 3];
      *(float4*)(op + g * 4) = r;
    }
  }
}

// ---------------------------------------------------------------------------
// Launch
// ---------------------------------------------------------------------------
extern "C" void kernel_launch(void* const* d_in, const int* in_sizes, int n_in,
                              void* d_out, int out_size, void* d_ws, size_t ws_size,
                              hipStream_t stream) {
  const float* x    = (const float*)d_in[0];  // [32,256,1024]
  const float* mask = (const float*)d_in[1];  // [32,256]
  const float* Wq   = (const float*)d_in[2];  // [1024,1024]
  const float* Wk   = (const float*)d_in[3];
  const float* Wv   = (const float*)d_in[4];
  float* out = (float*)d_out;

  u16* XB = (u16*)d_ws;                       // [8192][1024] bf16
  u16* WB = XB + (size_t)8192 * 1024;         // [3072][1024] (Wq,Wk,Wv stacked)

  cast_all<<<11264, 256, 0, stream>>>(x, Wq, Wk, Wv, XB, WB);
  fused_qkv_attn<<<1024, 512, 0, stream>>>(XB, WB, mask, out);
}